// Round 1
// baseline (295.754 us; speedup 1.0000x reference)
//
#include <hip/hip_runtime.h>

// Temporal shift: B=64, T=128, N=21, C=256, U=1.
// Partitions of C: [0,86) shift -1 (out[t]=x[t+1]); [86,171) shift 0;
// [171,256) shift +1 (out[t]=x[t-1]). Zero-fill out-of-range t.
// Layout (B,T,N,C) row-major: t-stride = N*C = 5376 floats = 1344 float4.

#define NT_T 128
#define NT_N 21
#define NT_C 256
#define T_STRIDE_F  (NT_N * NT_C)      // 5376 floats per t step
#define T_STRIDE_V  (T_STRIDE_F / 4)   // 1344 float4 per t step

__global__ __launch_bounds__(256) void temporal_shift_kernel(
    const float4* __restrict__ xv, float4* __restrict__ ov, int total_vec)
{
    int i = blockIdx.x * blockDim.x + threadIdx.x;
    if (i >= total_vec) return;

    int c4  = i & 63;        // C/4 = 64 vec-groups per (b,t,n) row
    int row = i >> 6;        // (b,t,n) row index
    int t   = (row / NT_N) & (NT_T - 1);   // T=128 is pow2

    // Uniform-shift groups: c4 in [0,20] -> s=-1 ; [22,41] -> s=0 ; [43,63] -> s=+1
    // Mixed groups: c4==21 (c 84..87 straddles 86), c4==42 (c 168..171 straddles 171)
    if (c4 != 21 && c4 != 42) {
        int s = (c4 <= 20) ? -1 : ((c4 <= 41) ? 0 : 1);
        int ts = t - s;
        if (ts >= 0 && ts < NT_T) {
            ov[i] = xv[i - s * T_STRIDE_V];
        } else {
            ov[i] = make_float4(0.f, 0.f, 0.f, 0.f);
        }
    } else {
        // Scalar path for the two boundary-straddling groups (2/64 lanes).
        const float* xf = (const float*)xv;
        float* of = (float*)ov;
        int base = i << 2;
        #pragma unroll
        for (int k = 0; k < 4; ++k) {
            int c = (c4 << 2) + k;
            int s = (c < 86) ? -1 : ((c < 171) ? 0 : 1);
            int ts = t - s;
            of[base + k] = (ts >= 0 && ts < NT_T)
                           ? xf[base + k - s * T_STRIDE_F]
                           : 0.f;
        }
    }
}

extern "C" void kernel_launch(void* const* d_in, const int* in_sizes, int n_in,
                              void* d_out, int out_size, void* d_ws, size_t ws_size,
                              hipStream_t stream)
{
    const float4* x = (const float4*)d_in[0];
    float4* out = (float4*)d_out;
    int total_vec = out_size / 4;   // 11,010,048 float4
    int block = 256;
    int grid = (total_vec + block - 1) / block;
    temporal_shift_kernel<<<grid, block, 0, stream>>>(x, out, total_vec);
}